// Round 5
// baseline (766.252 us; speedup 1.0000x reference)
//
#include <hip/hip_runtime.h>

#define BATCH 4
#define SEQ   2048
#define DIM   2048
#define NH    16
#define HD    128

typedef __bf16 bf16x8 __attribute__((ext_vector_type(8)));
typedef float  f32x4  __attribute__((ext_vector_type(4)));

__device__ __forceinline__ unsigned short f2bf(float f) {
  unsigned int u = __builtin_bit_cast(unsigned int, f);
  u += 0x7fffu + ((u >> 16) & 1u);          // RNE
  return (unsigned short)(u >> 16);
}

// async global->LDS, 16B per lane; LDS dest must be wave-uniform-base + lane*16
__device__ __forceinline__ void async16(void* lds, const void* g) {
  __builtin_amdgcn_global_load_lds(
      (const __attribute__((address_space(1))) unsigned int*)g,
      (__attribute__((address_space(3))) unsigned int*)lds, 16, 0, 0);
}

// ---------------------------------------------------------------- casts
__global__ __launch_bounds__(256) void cast_bf16_kernel(
    const float* __restrict__ src, unsigned short* __restrict__ dst, int n4) {
  int i = blockIdx.x * 256 + threadIdx.x;
  if (i >= n4) return;
  float4 v = ((const float4*)src)[i];
  ushort4 o;
  o.x = f2bf(v.x); o.y = f2bf(v.y); o.z = f2bf(v.z); o.w = f2bf(v.w);
  ((ushort4*)dst)[i] = o;
}

// all 4 weight matrices in one dispatch; dst = contiguous [Wq|Wk|Wv|Wo] bf16
__global__ __launch_bounds__(256) void cast4_kernel(
    const float* __restrict__ s0, const float* __restrict__ s1,
    const float* __restrict__ s2, const float* __restrict__ s3,
    unsigned short* __restrict__ dst) {
  int i = blockIdx.x * 256 + threadIdx.x;      // [0, 4 * 2^20)
  int sel = i >> 20, loc = i & 0xfffff;        // WE/4 = 2^20 float4 per matrix
  const float* s = sel == 0 ? s0 : sel == 1 ? s1 : sel == 2 ? s2 : s3;
  float4 v = ((const float4*)s)[loc];
  ushort4 o;
  o.x = f2bf(v.x); o.y = f2bf(v.y); o.z = f2bf(v.z); o.w = f2bf(v.w);
  ((ushort4*)dst)[i] = o;
}

// ---------------------------------------------------------------- RoPE cos/sin table: tab[s*64+fi] = (cos, sin)
__global__ __launch_bounds__(256) void rope_tab_kernel(float2* __restrict__ tab) {
  int idx = blockIdx.x * 256 + threadIdx.x;    // SEQ*64 threads
  int fi = idx & 63, s = idx >> 6;
  float ang = (float)s * exp2f(-(float)fi * 0.20762050593046932f);
  float cc, ss;
  sincosf(ang, &ss, &cc);
  tab[idx] = make_float2(cc, ss);
}

// ---------------------------------------------------------------- fused QKV GEMM + RoPE + V-transpose
// grid (48, 64): gx -> sel = gx>>4 (0=Q,1=K,2=V), h = gx&15; gy -> 128-row m-tile (b,s).
// Epilogue bounces the 128x128 fp32 tile through LDS in 4 chunks of 32 rows,
// applying table-driven RoPE for Q/K and a tile-transpose for V; 16B coalesced stores.
__global__ __launch_bounds__(256) void gemm_qkv(
    const unsigned short* __restrict__ A,    // xb (8192 x 2048) bf16
    const unsigned short* __restrict__ Wq,   // each (2048 x 2048) bf16, row = out-dim
    const unsigned short* __restrict__ Wk,
    const unsigned short* __restrict__ Wv,
    const float2* __restrict__ rtab,         // (SEQ, 64) cos/sin
    unsigned short* __restrict__ Qo,         // (B*H, S, HD) rope'd * CS
    unsigned short* __restrict__ Ko,         // (B*H, S, HD) rope'd
    unsigned short* __restrict__ Vto) {      // (B*H, HD, S)
  __shared__ unsigned short As[128 * 32];
  __shared__ unsigned short Bs[128 * 32];
  __shared__ float ep[32 * 132];
  const int tid = threadIdx.x;
  const int lane = tid & 63, wv = tid >> 6;
  const int q15 = lane & 15, quad = lane >> 4;
  const int wm = wv >> 1, wn = wv & 1;
  const int gx = blockIdx.x;
  const int sel = gx >> 4, h = gx & 15;
  const int m0 = blockIdx.y * 128;
  const unsigned short* Bw =
      (sel == 0 ? Wq : (sel == 1 ? Wk : Wv)) + (size_t)h * 128 * DIM;

  f32x4 acc[4][4] = {};

  for (int kt = 0; kt < DIM; kt += 32) {
    __syncthreads();
#pragma unroll
    for (int i = 0; i < 2; ++i) {
      int l = i * 256 + tid;
      int r = l >> 2, s = l & 3;
      int c = (s - (r >> 1)) & 3;
      async16(&As[l * 8], A + (size_t)(m0 + r) * DIM + kt + c * 8);
    }
#pragma unroll
    for (int i = 0; i < 2; ++i) {
      int l = i * 256 + tid;
      int r = l >> 2, s = l & 3;
      int c = (s - (r >> 1)) & 3;
      async16(&Bs[l * 8], Bw + (size_t)r * DIM + kt + c * 8);
    }
    __syncthreads();

    bf16x8 af[4], bf[4];
#pragma unroll
    for (int mf = 0; mf < 4; ++mf) {
      int r = wm * 64 + mf * 16 + q15;
      int sl = r * 4 + ((quad + (r >> 1)) & 3);
      af[mf] = *(const bf16x8*)&As[sl * 8];
    }
#pragma unroll
    for (int nf = 0; nf < 4; ++nf) {
      int r = wn * 64 + nf * 16 + q15;
      int sl = r * 4 + ((quad + (r >> 1)) & 3);
      bf[nf] = *(const bf16x8*)&Bs[sl * 8];
    }
#pragma unroll
    for (int mf = 0; mf < 4; ++mf)
#pragma unroll
      for (int nf = 0; nf < 4; ++nf)
        acc[mf][nf] = __builtin_amdgcn_mfma_f32_16x16x32_bf16(af[mf], bf[nf], acc[mf][nf], 0, 0, 0);
  }

  const int b = m0 >> 11;
  const int s0 = m0 & (SEQ - 1);
  const int bh = b * NH + h;
  const float CS = 0.12751744f;   // log2(e)/sqrt(HD), folded into Q

  for (int c = 0; c < 4; ++c) {
    __syncthreads();              // previous chunk's reads done
    if (wm == (c >> 1)) {
      int mfb = (c & 1) * 2;
#pragma unroll
      for (int mi = 0; mi < 2; ++mi) {
        int mf = mfb + mi;
        int rr0 = mf * 16 + quad * 4 - (c & 1) * 32;
#pragma unroll
        for (int nf = 0; nf < 4; ++nf) {
          int col = wn * 64 + nf * 16 + q15;
#pragma unroll
          for (int r = 0; r < 4; ++r)
            ep[(rr0 + r) * 132 + col] = acc[mf][nf][r];
        }
      }
    }
    __syncthreads();
#pragma unroll
    for (int oi = 0; oi < 2; ++oi) {
      int o = oi * 256 + tid;
      if (sel < 2) {
        int rr = o >> 4, oc = (o & 15) * 8;
        int s = s0 + c * 32 + rr;
        float4 a0 = *(const float4*)&ep[rr * 132 + oc];
        float4 a1 = *(const float4*)&ep[rr * 132 + oc + 4];
        float4 b0 = *(const float4*)&ep[rr * 132 + (oc ^ 64)];
        float4 b1 = *(const float4*)&ep[rr * 132 + (oc ^ 64) + 4];
        float av[8] = {a0.x, a0.y, a0.z, a0.w, a1.x, a1.y, a1.z, a1.w};
        float bv[8] = {b0.x, b0.y, b0.z, b0.w, b1.x, b1.y, b1.z, b1.w};
        float sgn = (oc & 64) ? 1.f : -1.f;   // lower half: t1*c - t2*s; upper: t2*c + t1*s
        float scl = (sel == 0) ? CS : 1.0f;
        const float2* rt = rtab + (size_t)s * 64 + (oc & 63);
        unsigned short u[8];
#pragma unroll
        for (int j = 0; j < 8; ++j) {
          float2 cs = rt[j];
          u[j] = f2bf((av[j] * cs.x + sgn * bv[j] * cs.y) * scl);
        }
        unsigned short* dst = (sel == 0 ? Qo : Ko) + ((size_t)bh * SEQ + s) * HD + oc;
        *(uint4*)dst = *(uint4*)u;
      } else {
        int hd = o & 127, so8 = (o >> 7) * 8;
        unsigned short u[8];
#pragma unroll
        for (int k = 0; k < 8; ++k)
          u[k] = f2bf(ep[(so8 + k) * 132 + hd]);
        *(uint4*)(Vto + ((size_t)bh * HD + hd) * SEQ + (s0 + c * 32 + so8)) = *(uint4*)u;
      }
    }
  }
}

// ---------------------------------------------------------------- O-projection GEMM: out[M,N] fp32 = A * Wo^T + bias
__global__ __launch_bounds__(256) void gemm_out(
    const unsigned short* __restrict__ A,
    const unsigned short* __restrict__ Bw,
    float* __restrict__ outf,
    const float* __restrict__ bias) {
  __shared__ unsigned short As[128 * 32];
  __shared__ unsigned short Bs[128 * 32];
  const int tid = threadIdx.x;
  const int lane = tid & 63, wv = tid >> 6;
  const int q15 = lane & 15, quad = lane >> 4;
  const int wm = wv >> 1, wn = wv & 1;
  const int n0 = blockIdx.x * 128, m0 = blockIdx.y * 128;

  f32x4 acc[4][4] = {};

  for (int kt = 0; kt < DIM; kt += 32) {
    __syncthreads();
#pragma unroll
    for (int i = 0; i < 2; ++i) {
      int l = i * 256 + tid;
      int r = l >> 2, s = l & 3;
      int c = (s - (r >> 1)) & 3;
      async16(&As[l * 8], A + (size_t)(m0 + r) * DIM + kt + c * 8);
    }
#pragma unroll
    for (int i = 0; i < 2; ++i) {
      int l = i * 256 + tid;
      int r = l >> 2, s = l & 3;
      int c = (s - (r >> 1)) & 3;
      async16(&Bs[l * 8], Bw + (size_t)(n0 + r) * DIM + kt + c * 8);
    }
    __syncthreads();

    bf16x8 af[4], bf[4];
#pragma unroll
    for (int mf = 0; mf < 4; ++mf) {
      int r = wm * 64 + mf * 16 + q15;
      int sl = r * 4 + ((quad + (r >> 1)) & 3);
      af[mf] = *(const bf16x8*)&As[sl * 8];
    }
#pragma unroll
    for (int nf = 0; nf < 4; ++nf) {
      int r = wn * 64 + nf * 16 + q15;
      int sl = r * 4 + ((quad + (r >> 1)) & 3);
      bf[nf] = *(const bf16x8*)&Bs[sl * 8];
    }
#pragma unroll
    for (int mf = 0; mf < 4; ++mf)
#pragma unroll
      for (int nf = 0; nf < 4; ++nf)
        acc[mf][nf] = __builtin_amdgcn_mfma_f32_16x16x32_bf16(af[mf], bf[nf], acc[mf][nf], 0, 0, 0);
  }

#pragma unroll
  for (int mf = 0; mf < 4; ++mf)
#pragma unroll
    for (int nf = 0; nf < 4; ++nf) {
      int col = n0 + wn * 64 + nf * 16 + q15;
      float bv = bias[col];
#pragma unroll
      for (int r = 0; r < 4; ++r) {
        int row = m0 + wm * 64 + mf * 16 + quad * 4 + r;
        outf[(size_t)row * DIM + col] = acc[mf][nf][r] + bv;
      }
    }
}

// ---------------------------------------------------------------- flash attention v4: paired q-tiles
// grid 512: block = (bh, t in 0..7); processes q-tile 8+t then 7-t sequentially ->
// every block stages exactly 34 KV tiles (uniform; no decay tail, no LPT needed).
// Per segment: 4 waves x 32 q rows, KV tiles of 64, St-swap (St = K·Q^T: softmax rows
// in-register), fixed-max softmax, Q pre-scaled by log2(e)/sqrt(HD).
__global__ __launch_bounds__(256) void attn_kernel(
    const unsigned short* __restrict__ Q,    // (B*H, S, HD) rope'd * CS
    const unsigned short* __restrict__ Kg,   // (B*H, S, HD) rope'd
    const unsigned short* __restrict__ Vt,   // (B*H, HD, S)
    unsigned short* __restrict__ O) {        // (B, S, H, HD) bf16
  __shared__ unsigned short Ks[64 * 128];
  __shared__ unsigned short Vs[128 * 64];
  __shared__ unsigned short Ps[4 * 32 * 72];
  const int tid = threadIdx.x;
  const int lane = tid & 63, wv = tid >> 6;
  const int q15 = lane & 15, quad = lane >> 4;
  const int bh = blockIdx.x & 63;
  const int t = blockIdx.x >> 6;             // 0..7
  const int b = bh >> 4, h = bh & 15;
  unsigned short* Pw = Ps + wv * (32 * 72);

  for (int seg = 0; seg < 2; ++seg) {
    const int qt = seg == 0 ? (8 + t) : (7 - t);
    const int q0w = qt * 128 + wv * 32;

    bf16x8 qf[2][4];
#pragma unroll
    for (int nq = 0; nq < 2; ++nq) {
      const unsigned short* qp = Q + ((size_t)bh * SEQ + q0w + nq * 16 + q15) * HD + quad * 8;
#pragma unroll
      for (int ks = 0; ks < 4; ++ks) qf[nq][ks] = *(const bf16x8*)(qp + ks * 32);
    }

    f32x4 oacc[2][8] = {};
    float rs[2] = {0.f, 0.f};
    const int jmax = 2 * qt + 2;
    const int jcap = 2 * qt + (wv >> 1);

    for (int j = 0; j < jmax; ++j) {
      const int kv0 = j * 64;
      __syncthreads();
#pragma unroll
      for (int i = 0; i < 4; ++i) {
        int l = i * 256 + tid;
        int r = l >> 4, c = (l & 15) ^ (r & 15);
        async16(&Ks[l * 8], Kg + ((size_t)bh * SEQ + kv0 + r) * HD + c * 8);
      }
#pragma unroll
      for (int i = 0; i < 4; ++i) {
        int l = i * 256 + tid;
        int r = l >> 3, c = (l & 7) ^ (r & 7);
        async16(&Vs[l * 8], Vt + ((size_t)bh * HD + r) * SEQ + kv0 + c * 8);
      }
      __syncthreads();

      if (j <= jcap) {
        const bool edge = (j == jcap);
#pragma unroll
        for (int mi = 0; mi < 4; ++mi) {
          f32x4 st[2] = {};
#pragma unroll
          for (int ks = 0; ks < 4; ++ks) {
            int r = mi * 16 + q15;
            int c = ks * 4 + quad;
            bf16x8 kf = *(const bf16x8*)&Ks[(r * 16 + (c ^ (r & 15))) * 8];
#pragma unroll
            for (int nq = 0; nq < 2; ++nq)
              st[nq] = __builtin_amdgcn_mfma_f32_16x16x32_bf16(kf, qf[nq][ks], st[nq], 0, 0, 0);
          }
#pragma unroll
          for (int nq = 0; nq < 2; ++nq) {
            unsigned int u[4];
#pragma unroll
            for (int r = 0; r < 4; ++r) {
              float p = exp2f(st[nq][r]);
              if (edge) {
                int kv = kv0 + mi * 16 + quad * 4 + r;
                int qq = q0w + nq * 16 + q15;
                p = (kv > qq) ? 0.f : p;
              }
              unsigned int uu = __builtin_bit_cast(unsigned int, p) & 0xffff0000u;
              rs[nq] += __builtin_bit_cast(float, uu);
              u[r] = uu;
            }
            uint2 pk;
            pk.x = (u[0] >> 16) | u[1];
            pk.y = (u[2] >> 16) | u[3];
            *(uint2*)&Pw[(nq * 16 + q15) * 72 + mi * 16 + quad * 4] = pk;
          }
        }
#pragma unroll
        for (int ks = 0; ks < 2; ++ks) {
          bf16x8 pf[2];
#pragma unroll
          for (int mq = 0; mq < 2; ++mq)
            pf[mq] = *(const bf16x8*)&Pw[(mq * 16 + q15) * 72 + ks * 32 + quad * 8];
#pragma unroll
          for (int nf = 0; nf < 8; ++nf) {
            int r = nf * 16 + q15;
            int c = ks * 4 + quad;
            bf16x8 vf = *(const bf16x8*)&Vs[(r * 8 + (c ^ (r & 7))) * 8];
#pragma unroll
            for (int mq = 0; mq < 2; ++mq)
              oacc[mq][nf] = __builtin_amdgcn_mfma_f32_16x16x32_bf16(pf[mq], vf, oacc[mq][nf], 0, 0, 0);
          }
        }
      }
    }

    // segment epilogue: reduce row sums across quads, write O
#pragma unroll
    for (int nq = 0; nq < 2; ++nq) {
      rs[nq] += __shfl_xor(rs[nq], 16);
      rs[nq] += __shfl_xor(rs[nq], 32);
    }
#pragma unroll
    for (int mq = 0; mq < 2; ++mq) {
#pragma unroll
      for (int r = 0; r < 4; ++r) {
        float l = __shfl(rs[mq], quad * 4 + r);
        float inv = 1.0f / l;
        int qq = q0w + mq * 16 + quad * 4 + r;
        size_t base = (((size_t)b * SEQ + qq) * NH + h) * HD;
#pragma unroll
        for (int nf = 0; nf < 8; ++nf)
          O[base + nf * 16 + q15] = f2bf(oacc[mq][nf][r] * inv);
      }
    }
  }
}

// ---------------------------------------------------------------- launch
extern "C" void kernel_launch(void* const* d_in, const int* in_sizes, int n_in,
                              void* d_out, int out_size, void* d_ws, size_t ws_size,
                              hipStream_t stream) {
  (void)in_sizes; (void)n_in; (void)out_size; (void)ws_size;
  const float* x  = (const float*)d_in[0];
  const float* Wq = (const float*)d_in[1];
  const float* Wk = (const float*)d_in[2];
  const float* Wv = (const float*)d_in[3];
  const float* Wo = (const float*)d_in[4];
  const float* bo = (const float*)d_in[5];
  float* out = (float*)d_out;

  const size_t XE = (size_t)BATCH * SEQ * DIM;   // 16.7M elems
  const size_t WE = (size_t)DIM * DIM;           // 4.2M elems

  char* p = (char*)d_ws;
  unsigned short* xb   = (unsigned short*)p; p += XE * 2;
  unsigned short* Wall = (unsigned short*)p; p += 4 * WE * 2;  // [Wq|Wk|Wv|Wo]
  unsigned short* Qg   = (unsigned short*)p; p += XE * 2;
  unsigned short* Kb   = (unsigned short*)p; p += XE * 2;
  unsigned short* Vtb  = (unsigned short*)p; p += XE * 2;
  unsigned short* attn = (unsigned short*)p; p += XE * 2;
  float2* rtab = (float2*)p; p += (size_t)SEQ * 64 * sizeof(float2);

  rope_tab_kernel<<<SEQ * 64 / 256, 256, 0, stream>>>(rtab);
  cast_bf16_kernel<<<(int)(XE / 4 / 256), 256, 0, stream>>>(x, xb, (int)(XE / 4));
  cast4_kernel<<<(int)(4 * WE / 4 / 256), 256, 0, stream>>>(Wq, Wk, Wv, Wo, Wall);

  gemm_qkv<<<dim3(48, 64), 256, 0, stream>>>(
      xb, Wall, Wall + WE, Wall + 2 * WE, rtab, Qg, Kb, Vtb);

  attn_kernel<<<dim3(512), 256, 0, stream>>>(Qg, Kb, Vtb, attn);

  gemm_out<<<dim3(DIM / 128, (BATCH * SEQ) / 128), 256, 0, stream>>>(
      attn, Wall + 3 * WE, out, bo);
}

// Round 6
// 711.417 us; speedup vs baseline: 1.0771x; 1.0771x over previous
//
#include <hip/hip_runtime.h>

#define BATCH 4
#define SEQ   2048
#define DIM   2048
#define NH    16
#define HD    128

typedef __bf16 bf16x8 __attribute__((ext_vector_type(8)));
typedef float  f32x4  __attribute__((ext_vector_type(4)));

__device__ __forceinline__ unsigned short f2bf(float f) {
  unsigned int u = __builtin_bit_cast(unsigned int, f);
  u += 0x7fffu + ((u >> 16) & 1u);          // RNE
  return (unsigned short)(u >> 16);
}

// async global->LDS, 16B per lane; LDS dest must be wave-uniform-base + lane*16
__device__ __forceinline__ void async16(void* lds, const void* g) {
  __builtin_amdgcn_global_load_lds(
      (const __attribute__((address_space(1))) unsigned int*)g,
      (__attribute__((address_space(3))) unsigned int*)lds, 16, 0, 0);
}

// ---------------------------------------------------------------- casts
__global__ __launch_bounds__(256) void cast_bf16_kernel(
    const float* __restrict__ src, unsigned short* __restrict__ dst, int n4) {
  int i = blockIdx.x * 256 + threadIdx.x;
  if (i >= n4) return;
  float4 v = ((const float4*)src)[i];
  ushort4 o;
  o.x = f2bf(v.x); o.y = f2bf(v.y); o.z = f2bf(v.z); o.w = f2bf(v.w);
  ((ushort4*)dst)[i] = o;
}

// all 4 weight matrices in one dispatch; dst = contiguous [Wq|Wk|Wv|Wo] bf16
__global__ __launch_bounds__(256) void cast4_kernel(
    const float* __restrict__ s0, const float* __restrict__ s1,
    const float* __restrict__ s2, const float* __restrict__ s3,
    unsigned short* __restrict__ dst) {
  int i = blockIdx.x * 256 + threadIdx.x;      // [0, 4 * 2^20)
  int sel = i >> 20, loc = i & 0xfffff;        // WE/4 = 2^20 float4 per matrix
  const float* s = sel == 0 ? s0 : sel == 1 ? s1 : sel == 2 ? s2 : s3;
  float4 v = ((const float4*)s)[loc];
  ushort4 o;
  o.x = f2bf(v.x); o.y = f2bf(v.y); o.z = f2bf(v.z); o.w = f2bf(v.w);
  ((ushort4*)dst)[i] = o;
}

// ---------------------------------------------------------------- fused QKV GEMM + RoPE + V-transpose
// grid (48, 64): gx -> sel = gx>>4 (0=Q,1=K,2=V), h = gx&15; gy -> 128-row m-tile (b,s).
// Epilogue bounces the 128x128 fp32 tile through LDS in 4 chunks of 32 rows,
// applying inline-sincosf RoPE for Q/K and a tile-transpose for V; 16B coalesced stores.
// NOTE (R5 lesson): a global cos/sin table regressed -65us — table streams miss L2
// under GEMM traffic (+43MB FETCH) and the epilogue stalls on dependent loads; the
// sincosf VALU work overlaps with the MFMA pipe instead. Keep it inline.
__global__ __launch_bounds__(256) void gemm_qkv(
    const unsigned short* __restrict__ A,    // xb (8192 x 2048) bf16
    const unsigned short* __restrict__ Wq,   // each (2048 x 2048) bf16, row = out-dim
    const unsigned short* __restrict__ Wk,
    const unsigned short* __restrict__ Wv,
    unsigned short* __restrict__ Qo,         // (B*H, S, HD) rope'd * CS
    unsigned short* __restrict__ Ko,         // (B*H, S, HD) rope'd
    unsigned short* __restrict__ Vto) {      // (B*H, HD, S)
  __shared__ unsigned short As[128 * 32];
  __shared__ unsigned short Bs[128 * 32];
  __shared__ float ep[32 * 132];
  const int tid = threadIdx.x;
  const int lane = tid & 63, wv = tid >> 6;
  const int q15 = lane & 15, quad = lane >> 4;
  const int wm = wv >> 1, wn = wv & 1;
  const int gx = blockIdx.x;
  const int sel = gx >> 4, h = gx & 15;
  const int m0 = blockIdx.y * 128;
  const unsigned short* Bw =
      (sel == 0 ? Wq : (sel == 1 ? Wk : Wv)) + (size_t)h * 128 * DIM;

  f32x4 acc[4][4] = {};

  for (int kt = 0; kt < DIM; kt += 32) {
    __syncthreads();
#pragma unroll
    for (int i = 0; i < 2; ++i) {
      int l = i * 256 + tid;
      int r = l >> 2, s = l & 3;
      int c = (s - (r >> 1)) & 3;
      async16(&As[l * 8], A + (size_t)(m0 + r) * DIM + kt + c * 8);
    }
#pragma unroll
    for (int i = 0; i < 2; ++i) {
      int l = i * 256 + tid;
      int r = l >> 2, s = l & 3;
      int c = (s - (r >> 1)) & 3;
      async16(&Bs[l * 8], Bw + (size_t)r * DIM + kt + c * 8);
    }
    __syncthreads();

    bf16x8 af[4], bf[4];
#pragma unroll
    for (int mf = 0; mf < 4; ++mf) {
      int r = wm * 64 + mf * 16 + q15;
      int sl = r * 4 + ((quad + (r >> 1)) & 3);
      af[mf] = *(const bf16x8*)&As[sl * 8];
    }
#pragma unroll
    for (int nf = 0; nf < 4; ++nf) {
      int r = wn * 64 + nf * 16 + q15;
      int sl = r * 4 + ((quad + (r >> 1)) & 3);
      bf[nf] = *(const bf16x8*)&Bs[sl * 8];
    }
#pragma unroll
    for (int mf = 0; mf < 4; ++mf)
#pragma unroll
      for (int nf = 0; nf < 4; ++nf)
        acc[mf][nf] = __builtin_amdgcn_mfma_f32_16x16x32_bf16(af[mf], bf[nf], acc[mf][nf], 0, 0, 0);
  }

  const int b = m0 >> 11;
  const int s0 = m0 & (SEQ - 1);
  const int bh = b * NH + h;
  const float CS = 0.12751744f;   // log2(e)/sqrt(HD), folded into Q

  for (int c = 0; c < 4; ++c) {
    __syncthreads();              // previous chunk's reads done
    if (wm == (c >> 1)) {
      int mfb = (c & 1) * 2;
#pragma unroll
      for (int mi = 0; mi < 2; ++mi) {
        int mf = mfb + mi;
        int rr0 = mf * 16 + quad * 4 - (c & 1) * 32;
#pragma unroll
        for (int nf = 0; nf < 4; ++nf) {
          int col = wn * 64 + nf * 16 + q15;
#pragma unroll
          for (int r = 0; r < 4; ++r)
            ep[(rr0 + r) * 132 + col] = acc[mf][nf][r];
        }
      }
    }
    __syncthreads();
#pragma unroll
    for (int oi = 0; oi < 2; ++oi) {
      int o = oi * 256 + tid;
      if (sel < 2) {
        int rr = o >> 4, oc = (o & 15) * 8;
        int s = s0 + c * 32 + rr;
        float4 a0 = *(const float4*)&ep[rr * 132 + oc];
        float4 a1 = *(const float4*)&ep[rr * 132 + oc + 4];
        float4 b0 = *(const float4*)&ep[rr * 132 + (oc ^ 64)];
        float4 b1 = *(const float4*)&ep[rr * 132 + (oc ^ 64) + 4];
        float av[8] = {a0.x, a0.y, a0.z, a0.w, a1.x, a1.y, a1.z, a1.w};
        float bv[8] = {b0.x, b0.y, b0.z, b0.w, b1.x, b1.y, b1.z, b1.w};
        float sgn = (oc & 64) ? 1.f : -1.f;   // lower half: t1*c - t2*s; upper: t2*c + t1*s
        float scl = (sel == 0) ? CS : 1.0f;
        unsigned short u[8];
#pragma unroll
        for (int j = 0; j < 8; ++j) {
          int fi = (oc & 63) + j;
          float ang = (float)s * exp2f(-(float)fi * 0.20762050593046932f);
          float cc, ss;
          sincosf(ang, &ss, &cc);
          u[j] = f2bf((av[j] * cc + sgn * bv[j] * ss) * scl);
        }
        unsigned short* dst = (sel == 0 ? Qo : Ko) + ((size_t)bh * SEQ + s) * HD + oc;
        *(uint4*)dst = *(uint4*)u;
      } else {
        int hd = o & 127, so8 = (o >> 7) * 8;
        unsigned short u[8];
#pragma unroll
        for (int k = 0; k < 8; ++k)
          u[k] = f2bf(ep[(so8 + k) * 132 + hd]);
        *(uint4*)(Vto + ((size_t)bh * HD + hd) * SEQ + (s0 + c * 32 + so8)) = *(uint4*)u;
      }
    }
  }
}

// ---------------------------------------------------------------- O-projection GEMM: out[M,N] fp32 = A * Wo^T + bias
__global__ __launch_bounds__(256) void gemm_out(
    const unsigned short* __restrict__ A,
    const unsigned short* __restrict__ Bw,
    float* __restrict__ outf,
    const float* __restrict__ bias) {
  __shared__ unsigned short As[128 * 32];
  __shared__ unsigned short Bs[128 * 32];
  const int tid = threadIdx.x;
  const int lane = tid & 63, wv = tid >> 6;
  const int q15 = lane & 15, quad = lane >> 4;
  const int wm = wv >> 1, wn = wv & 1;
  const int n0 = blockIdx.x * 128, m0 = blockIdx.y * 128;

  f32x4 acc[4][4] = {};

  for (int kt = 0; kt < DIM; kt += 32) {
    __syncthreads();
#pragma unroll
    for (int i = 0; i < 2; ++i) {
      int l = i * 256 + tid;
      int r = l >> 2, s = l & 3;
      int c = (s - (r >> 1)) & 3;
      async16(&As[l * 8], A + (size_t)(m0 + r) * DIM + kt + c * 8);
    }
#pragma unroll
    for (int i = 0; i < 2; ++i) {
      int l = i * 256 + tid;
      int r = l >> 2, s = l & 3;
      int c = (s - (r >> 1)) & 3;
      async16(&Bs[l * 8], Bw + (size_t)(n0 + r) * DIM + kt + c * 8);
    }
    __syncthreads();

    bf16x8 af[4], bf[4];
#pragma unroll
    for (int mf = 0; mf < 4; ++mf) {
      int r = wm * 64 + mf * 16 + q15;
      int sl = r * 4 + ((quad + (r >> 1)) & 3);
      af[mf] = *(const bf16x8*)&As[sl * 8];
    }
#pragma unroll
    for (int nf = 0; nf < 4; ++nf) {
      int r = wn * 64 + nf * 16 + q15;
      int sl = r * 4 + ((quad + (r >> 1)) & 3);
      bf[nf] = *(const bf16x8*)&Bs[sl * 8];
    }
#pragma unroll
    for (int mf = 0; mf < 4; ++mf)
#pragma unroll
      for (int nf = 0; nf < 4; ++nf)
        acc[mf][nf] = __builtin_amdgcn_mfma_f32_16x16x32_bf16(af[mf], bf[nf], acc[mf][nf], 0, 0, 0);
  }

#pragma unroll
  for (int mf = 0; mf < 4; ++mf)
#pragma unroll
    for (int nf = 0; nf < 4; ++nf) {
      int col = n0 + wn * 64 + nf * 16 + q15;
      float bv = bias[col];
#pragma unroll
      for (int r = 0; r < 4; ++r) {
        int row = m0 + wm * 64 + mf * 16 + quad * 4 + r;
        outf[(size_t)row * DIM + col] = acc[mf][nf][r] + bv;
      }
    }
}

// ---------------------------------------------------------------- flash attention v5: hybrid grid 768
// Per bh: t in 0..11. t<8: single q-tile qt=15-t (32..18 iters, heavy-first LPT).
// t>=8: paired q-tiles {7-(t-8), t-8} = 18 iters total. Every block >=18 iters,
// 768 blocks = 3 blocks/CU co-resident (LDS 50KB x3 = 150 <= 160).
// Per segment: 4 waves x 32 q rows, KV tiles of 64, St-swap (St = K·Q^T: softmax rows
// in-register), fixed-max softmax, Q pre-scaled by log2(e)/sqrt(HD).
__global__ __launch_bounds__(256) void attn_kernel(
    const unsigned short* __restrict__ Q,    // (B*H, S, HD) rope'd * CS
    const unsigned short* __restrict__ Kg,   // (B*H, S, HD) rope'd
    const unsigned short* __restrict__ Vt,   // (B*H, HD, S)
    unsigned short* __restrict__ O) {        // (B, S, H, HD) bf16
  __shared__ unsigned short Ks[64 * 128];
  __shared__ unsigned short Vs[128 * 64];
  __shared__ unsigned short Ps[4 * 32 * 72];
  const int tid = threadIdx.x;
  const int lane = tid & 63, wv = tid >> 6;
  const int q15 = lane & 15, quad = lane >> 4;
  const int bh = blockIdx.x & 63;
  const int t = blockIdx.x >> 6;             // 0..11
  const int nseg = (t < 8) ? 1 : 2;
  const int b = bh >> 4, h = bh & 15;
  unsigned short* Pw = Ps + wv * (32 * 72);

  for (int seg = 0; seg < nseg; ++seg) {
    const int qt = (t < 8) ? (15 - t) : (seg == 0 ? (15 - t) : (t - 8));
    const int q0w = qt * 128 + wv * 32;

    bf16x8 qf[2][4];
#pragma unroll
    for (int nq = 0; nq < 2; ++nq) {
      const unsigned short* qp = Q + ((size_t)bh * SEQ + q0w + nq * 16 + q15) * HD + quad * 8;
#pragma unroll
      for (int ks = 0; ks < 4; ++ks) qf[nq][ks] = *(const bf16x8*)(qp + ks * 32);
    }

    f32x4 oacc[2][8] = {};
    float rs[2] = {0.f, 0.f};
    const int jmax = 2 * qt + 2;
    const int jcap = 2 * qt + (wv >> 1);

    for (int j = 0; j < jmax; ++j) {
      const int kv0 = j * 64;
      __syncthreads();
#pragma unroll
      for (int i = 0; i < 4; ++i) {
        int l = i * 256 + tid;
        int r = l >> 4, c = (l & 15) ^ (r & 15);
        async16(&Ks[l * 8], Kg + ((size_t)bh * SEQ + kv0 + r) * HD + c * 8);
      }
#pragma unroll
      for (int i = 0; i < 4; ++i) {
        int l = i * 256 + tid;
        int r = l >> 3, c = (l & 7) ^ (r & 7);
        async16(&Vs[l * 8], Vt + ((size_t)bh * HD + r) * SEQ + kv0 + c * 8);
      }
      __syncthreads();

      if (j <= jcap) {
        const bool edge = (j == jcap);
#pragma unroll
        for (int mi = 0; mi < 4; ++mi) {
          f32x4 st[2] = {};
#pragma unroll
          for (int ks = 0; ks < 4; ++ks) {
            int r = mi * 16 + q15;
            int c = ks * 4 + quad;
            bf16x8 kf = *(const bf16x8*)&Ks[(r * 16 + (c ^ (r & 15))) * 8];
#pragma unroll
            for (int nq = 0; nq < 2; ++nq)
              st[nq] = __builtin_amdgcn_mfma_f32_16x16x32_bf16(kf, qf[nq][ks], st[nq], 0, 0, 0);
          }
#pragma unroll
          for (int nq = 0; nq < 2; ++nq) {
            unsigned int u[4];
#pragma unroll
            for (int r = 0; r < 4; ++r) {
              float p = exp2f(st[nq][r]);
              if (edge) {
                int kv = kv0 + mi * 16 + quad * 4 + r;
                int qq = q0w + nq * 16 + q15;
                p = (kv > qq) ? 0.f : p;
              }
              unsigned int uu = __builtin_bit_cast(unsigned int, p) & 0xffff0000u;
              rs[nq] += __builtin_bit_cast(float, uu);
              u[r] = uu;
            }
            uint2 pk;
            pk.x = (u[0] >> 16) | u[1];
            pk.y = (u[2] >> 16) | u[3];
            *(uint2*)&Pw[(nq * 16 + q15) * 72 + mi * 16 + quad * 4] = pk;
          }
        }
#pragma unroll
        for (int ks = 0; ks < 2; ++ks) {
          bf16x8 pf[2];
#pragma unroll
          for (int mq = 0; mq < 2; ++mq)
            pf[mq] = *(const bf16x8*)&Pw[(mq * 16 + q15) * 72 + ks * 32 + quad * 8];
#pragma unroll
          for (int nf = 0; nf < 8; ++nf) {
            int r = nf * 16 + q15;
            int c = ks * 4 + quad;
            bf16x8 vf = *(const bf16x8*)&Vs[(r * 8 + (c ^ (r & 7))) * 8];
#pragma unroll
            for (int mq = 0; mq < 2; ++mq)
              oacc[mq][nf] = __builtin_amdgcn_mfma_f32_16x16x32_bf16(pf[mq], vf, oacc[mq][nf], 0, 0, 0);
          }
        }
      }
    }

    // segment epilogue: reduce row sums across quads, write O
#pragma unroll
    for (int nq = 0; nq < 2; ++nq) {
      rs[nq] += __shfl_xor(rs[nq], 16);
      rs[nq] += __shfl_xor(rs[nq], 32);
    }
#pragma unroll
    for (int mq = 0; mq < 2; ++mq) {
#pragma unroll
      for (int r = 0; r < 4; ++r) {
        float l = __shfl(rs[mq], quad * 4 + r);
        float inv = 1.0f / l;
        int qq = q0w + mq * 16 + quad * 4 + r;
        size_t base = (((size_t)b * SEQ + qq) * NH + h) * HD;
#pragma unroll
        for (int nf = 0; nf < 8; ++nf)
          O[base + nf * 16 + q15] = f2bf(oacc[mq][nf][r] * inv);
      }
    }
  }
}

// ---------------------------------------------------------------- launch
extern "C" void kernel_launch(void* const* d_in, const int* in_sizes, int n_in,
                              void* d_out, int out_size, void* d_ws, size_t ws_size,
                              hipStream_t stream) {
  (void)in_sizes; (void)n_in; (void)out_size; (void)ws_size;
  const float* x  = (const float*)d_in[0];
  const float* Wq = (const float*)d_in[1];
  const float* Wk = (const float*)d_in[2];
  const float* Wv = (const float*)d_in[3];
  const float* Wo = (const float*)d_in[4];
  const float* bo = (const float*)d_in[5];
  float* out = (float*)d_out;

  const size_t XE = (size_t)BATCH * SEQ * DIM;   // 16.7M elems
  const size_t WE = (size_t)DIM * DIM;           // 4.2M elems

  char* p = (char*)d_ws;
  unsigned short* xb   = (unsigned short*)p; p += XE * 2;
  unsigned short* Wall = (unsigned short*)p; p += 4 * WE * 2;  // [Wq|Wk|Wv|Wo]
  unsigned short* Qg   = (unsigned short*)p; p += XE * 2;
  unsigned short* Kb   = (unsigned short*)p; p += XE * 2;
  unsigned short* Vtb  = (unsigned short*)p; p += XE * 2;
  unsigned short* attn = (unsigned short*)p; p += XE * 2;

  cast_bf16_kernel<<<(int)(XE / 4 / 256), 256, 0, stream>>>(x, xb, (int)(XE / 4));
  cast4_kernel<<<(int)(4 * WE / 4 / 256), 256, 0, stream>>>(Wq, Wk, Wv, Wo, Wall);

  gemm_qkv<<<dim3(48, 64), 256, 0, stream>>>(
      xb, Wall, Wall + WE, Wall + 2 * WE, Qg, Kb, Vtb);

  attn_kernel<<<dim3(768), 256, 0, stream>>>(Qg, Kb, Vtb, attn);

  gemm_out<<<dim3(DIM / 128, (BATCH * SEQ) / 128), 256, 0, stream>>>(
      attn, Wall + 3 * WE, out, bo);
}

// Round 7
// 692.413 us; speedup vs baseline: 1.1066x; 1.0274x over previous
//
#include <hip/hip_runtime.h>

#define BATCH 4
#define SEQ   2048
#define DIM   2048
#define NH    16
#define HD    128

typedef __bf16 bf16x8 __attribute__((ext_vector_type(8)));
typedef float  f32x4  __attribute__((ext_vector_type(4)));

__device__ __forceinline__ unsigned short f2bf(float f) {
  unsigned int u = __builtin_bit_cast(unsigned int, f);
  u += 0x7fffu + ((u >> 16) & 1u);          // RNE
  return (unsigned short)(u >> 16);
}

// async global->LDS, 16B per lane; LDS dest must be wave-uniform-base + lane*16
__device__ __forceinline__ void async16(void* lds, const void* g) {
  __builtin_amdgcn_global_load_lds(
      (const __attribute__((address_space(1))) unsigned int*)g,
      (__attribute__((address_space(3))) unsigned int*)lds, 16, 0, 0);
}

// ---------------------------------------------------------------- one cast dispatch for x + all 4 weights
// dst layout [xb | Wq | Wk | Wv | Wo] is contiguous in the workspace.
__global__ __launch_bounds__(256) void cast_all_kernel(
    const float* __restrict__ x,
    const float* __restrict__ w0, const float* __restrict__ w1,
    const float* __restrict__ w2, const float* __restrict__ w3,
    unsigned short* __restrict__ dst) {
  int i = blockIdx.x * 256 + threadIdx.x;      // [0, 2*XE/4); XE/4 = 4M float4
  const float* s;
  int loc;
  if (i < (1 << 22)) { s = x; loc = i; }       // x: 2^22 float4
  else {
    int k = i - (1 << 22);                     // weights: 4 x 2^20 float4
    int sel = k >> 20; loc = k & 0xfffff;
    s = sel == 0 ? w0 : sel == 1 ? w1 : sel == 2 ? w2 : w3;
  }
  float4 v = ((const float4*)s)[loc];
  ushort4 o;
  o.x = f2bf(v.x); o.y = f2bf(v.y); o.z = f2bf(v.z); o.w = f2bf(v.w);
  ((ushort4*)dst)[i] = o;
}

// ---------------------------------------------------------------- fused QKV GEMM + RoPE + V-transpose
// grid (48, 64): gx -> sel = gx>>4 (0=Q,1=K,2=V), h = gx&15; gy -> 128-row m-tile (b,s).
// Epilogue bounces the 128x128 fp32 tile through LDS in 4 chunks of 32 rows,
// applying RoPE for Q/K and a tile-transpose for V; 16B coalesced stores.
// R5 lesson: global cos/sin table regressed (-65us: L2 misses + dependent-load stalls);
// keep trig inline — it overlaps the MFMA pipe. R7: inv_freq hoisted (c-invariant) and
// sincosf -> __sinf/__cosf (hw v_sin, no Payne-Hanek big-arg reduction; angle err
// ~1e-4 rad << bf16 rounding).
__global__ __launch_bounds__(256) void gemm_qkv(
    const unsigned short* __restrict__ A,    // xb (8192 x 2048) bf16
    const unsigned short* __restrict__ Wq,   // each (2048 x 2048) bf16, row = out-dim
    const unsigned short* __restrict__ Wk,
    const unsigned short* __restrict__ Wv,
    unsigned short* __restrict__ Qo,         // (B*H, S, HD) rope'd * CS
    unsigned short* __restrict__ Ko,         // (B*H, S, HD) rope'd
    unsigned short* __restrict__ Vto) {      // (B*H, HD, S)
  __shared__ unsigned short As[128 * 32];
  __shared__ unsigned short Bs[128 * 32];
  __shared__ float ep[32 * 132];
  const int tid = threadIdx.x;
  const int lane = tid & 63, wv = tid >> 6;
  const int q15 = lane & 15, quad = lane >> 4;
  const int wm = wv >> 1, wn = wv & 1;
  const int gx = blockIdx.x;
  const int sel = gx >> 4, h = gx & 15;
  const int m0 = blockIdx.y * 128;
  const unsigned short* Bw =
      (sel == 0 ? Wq : (sel == 1 ? Wk : Wv)) + (size_t)h * 128 * DIM;

  f32x4 acc[4][4] = {};

  for (int kt = 0; kt < DIM; kt += 32) {
    __syncthreads();
#pragma unroll
    for (int i = 0; i < 2; ++i) {
      int l = i * 256 + tid;
      int r = l >> 2, s = l & 3;
      int c = (s - (r >> 1)) & 3;
      async16(&As[l * 8], A + (size_t)(m0 + r) * DIM + kt + c * 8);
    }
#pragma unroll
    for (int i = 0; i < 2; ++i) {
      int l = i * 256 + tid;
      int r = l >> 2, s = l & 3;
      int c = (s - (r >> 1)) & 3;
      async16(&Bs[l * 8], Bw + (size_t)r * DIM + kt + c * 8);
    }
    __syncthreads();

    bf16x8 af[4], bf[4];
#pragma unroll
    for (int mf = 0; mf < 4; ++mf) {
      int r = wm * 64 + mf * 16 + q15;
      int sl = r * 4 + ((quad + (r >> 1)) & 3);
      af[mf] = *(const bf16x8*)&As[sl * 8];
    }
#pragma unroll
    for (int nf = 0; nf < 4; ++nf) {
      int r = wn * 64 + nf * 16 + q15;
      int sl = r * 4 + ((quad + (r >> 1)) & 3);
      bf[nf] = *(const bf16x8*)&Bs[sl * 8];
    }
#pragma unroll
    for (int mf = 0; mf < 4; ++mf)
#pragma unroll
      for (int nf = 0; nf < 4; ++nf)
        acc[mf][nf] = __builtin_amdgcn_mfma_f32_16x16x32_bf16(af[mf], bf[nf], acc[mf][nf], 0, 0, 0);
  }

  const int b = m0 >> 11;
  const int s0 = m0 & (SEQ - 1);
  const int bh = b * NH + h;
  const float CS = 0.12751744f;   // log2(e)/sqrt(HD), folded into Q

  // hoisted inv_freq (c-loop invariant): one value per (oi, j)
  float invf[2][8];
  if (sel < 2) {
#pragma unroll
    for (int oi = 0; oi < 2; ++oi) {
      int oc = ((oi * 256 + tid) & 15) * 8;
#pragma unroll
      for (int j = 0; j < 8; ++j)
        invf[oi][j] = exp2f(-(float)((oc & 63) + j) * 0.20762050593046932f);
    }
  }

  for (int c = 0; c < 4; ++c) {
    __syncthreads();              // previous chunk's reads done
    if (wm == (c >> 1)) {
      int mfb = (c & 1) * 2;
#pragma unroll
      for (int mi = 0; mi < 2; ++mi) {
        int mf = mfb + mi;
        int rr0 = mf * 16 + quad * 4 - (c & 1) * 32;
#pragma unroll
        for (int nf = 0; nf < 4; ++nf) {
          int col = wn * 64 + nf * 16 + q15;
#pragma unroll
          for (int r = 0; r < 4; ++r)
            ep[(rr0 + r) * 132 + col] = acc[mf][nf][r];
        }
      }
    }
    __syncthreads();
#pragma unroll
    for (int oi = 0; oi < 2; ++oi) {
      int o = oi * 256 + tid;
      if (sel < 2) {
        int rr = o >> 4, oc = (o & 15) * 8;
        int s = s0 + c * 32 + rr;
        float sf = (float)s;
        float4 a0 = *(const float4*)&ep[rr * 132 + oc];
        float4 a1 = *(const float4*)&ep[rr * 132 + oc + 4];
        float4 b0 = *(const float4*)&ep[rr * 132 + (oc ^ 64)];
        float4 b1 = *(const float4*)&ep[rr * 132 + (oc ^ 64) + 4];
        float av[8] = {a0.x, a0.y, a0.z, a0.w, a1.x, a1.y, a1.z, a1.w};
        float bv[8] = {b0.x, b0.y, b0.z, b0.w, b1.x, b1.y, b1.z, b1.w};
        float sgn = (oc & 64) ? 1.f : -1.f;   // lower half: t1*c - t2*s; upper: t2*c + t1*s
        float scl = (sel == 0) ? CS : 1.0f;
        unsigned short u[8];
#pragma unroll
        for (int j = 0; j < 8; ++j) {
          float ang = sf * invf[oi][j];
          float cc = __cosf(ang), ss = __sinf(ang);
          u[j] = f2bf((av[j] * cc + sgn * bv[j] * ss) * scl);
        }
        unsigned short* dst = (sel == 0 ? Qo : Ko) + ((size_t)bh * SEQ + s) * HD + oc;
        *(uint4*)dst = *(uint4*)u;
      } else {
        int hd = o & 127, so8 = (o >> 7) * 8;
        unsigned short u[8];
#pragma unroll
        for (int k = 0; k < 8; ++k)
          u[k] = f2bf(ep[(so8 + k) * 132 + hd]);
        *(uint4*)(Vto + ((size_t)bh * HD + hd) * SEQ + (s0 + c * 32 + so8)) = *(uint4*)u;
      }
    }
  }
}

// ---------------------------------------------------------------- O-projection GEMM: out[M,N] fp32 = A * Wo^T + bias
__global__ __launch_bounds__(256) void gemm_out(
    const unsigned short* __restrict__ A,
    const unsigned short* __restrict__ Bw,
    float* __restrict__ outf,
    const float* __restrict__ bias) {
  __shared__ unsigned short As[128 * 32];
  __shared__ unsigned short Bs[128 * 32];
  const int tid = threadIdx.x;
  const int lane = tid & 63, wv = tid >> 6;
  const int q15 = lane & 15, quad = lane >> 4;
  const int wm = wv >> 1, wn = wv & 1;
  const int n0 = blockIdx.x * 128, m0 = blockIdx.y * 128;

  f32x4 acc[4][4] = {};

  for (int kt = 0; kt < DIM; kt += 32) {
    __syncthreads();
#pragma unroll
    for (int i = 0; i < 2; ++i) {
      int l = i * 256 + tid;
      int r = l >> 2, s = l & 3;
      int c = (s - (r >> 1)) & 3;
      async16(&As[l * 8], A + (size_t)(m0 + r) * DIM + kt + c * 8);
    }
#pragma unroll
    for (int i = 0; i < 2; ++i) {
      int l = i * 256 + tid;
      int r = l >> 2, s = l & 3;
      int c = (s - (r >> 1)) & 3;
      async16(&Bs[l * 8], Bw + (size_t)(n0 + r) * DIM + kt + c * 8);
    }
    __syncthreads();

    bf16x8 af[4], bf[4];
#pragma unroll
    for (int mf = 0; mf < 4; ++mf) {
      int r = wm * 64 + mf * 16 + q15;
      int sl = r * 4 + ((quad + (r >> 1)) & 3);
      af[mf] = *(const bf16x8*)&As[sl * 8];
    }
#pragma unroll
    for (int nf = 0; nf < 4; ++nf) {
      int r = wn * 64 + nf * 16 + q15;
      int sl = r * 4 + ((quad + (r >> 1)) & 3);
      bf[nf] = *(const bf16x8*)&Bs[sl * 8];
    }
#pragma unroll
    for (int mf = 0; mf < 4; ++mf)
#pragma unroll
      for (int nf = 0; nf < 4; ++nf)
        acc[mf][nf] = __builtin_amdgcn_mfma_f32_16x16x32_bf16(af[mf], bf[nf], acc[mf][nf], 0, 0, 0);
  }

#pragma unroll
  for (int mf = 0; mf < 4; ++mf)
#pragma unroll
    for (int nf = 0; nf < 4; ++nf) {
      int col = n0 + wn * 64 + nf * 16 + q15;
      float bv = bias[col];
#pragma unroll
      for (int r = 0; r < 4; ++r) {
        int row = m0 + wm * 64 + mf * 16 + quad * 4 + r;
        outf[(size_t)row * DIM + col] = acc[mf][nf][r] + bv;
      }
    }
}

// ---------------------------------------------------------------- flash attention (R6 structure, validated)
// Per bh: t in 0..11. t<8: single q-tile qt=15-t; t>=8: paired {15-t, t-8} = 18 iters.
// 768 blocks = 3 blocks/CU co-resident. 4 waves x 32 q rows, KV tiles of 64,
// St-swap (softmax rows in-register), fixed-max softmax, Q pre-scaled.
__global__ __launch_bounds__(256) void attn_kernel(
    const unsigned short* __restrict__ Q,    // (B*H, S, HD) rope'd * CS
    const unsigned short* __restrict__ Kg,   // (B*H, S, HD) rope'd
    const unsigned short* __restrict__ Vt,   // (B*H, HD, S)
    unsigned short* __restrict__ O) {        // (B, S, H, HD) bf16
  __shared__ unsigned short Ks[64 * 128];
  __shared__ unsigned short Vs[128 * 64];
  __shared__ unsigned short Ps[4 * 32 * 72];
  const int tid = threadIdx.x;
  const int lane = tid & 63, wv = tid >> 6;
  const int q15 = lane & 15, quad = lane >> 4;
  const int bh = blockIdx.x & 63;
  const int t = blockIdx.x >> 6;             // 0..11
  const int nseg = (t < 8) ? 1 : 2;
  const int b = bh >> 4, h = bh & 15;
  unsigned short* Pw = Ps + wv * (32 * 72);

  for (int seg = 0; seg < nseg; ++seg) {
    const int qt = (t < 8) ? (15 - t) : (seg == 0 ? (15 - t) : (t - 8));
    const int q0w = qt * 128 + wv * 32;

    bf16x8 qf[2][4];
#pragma unroll
    for (int nq = 0; nq < 2; ++nq) {
      const unsigned short* qp = Q + ((size_t)bh * SEQ + q0w + nq * 16 + q15) * HD + quad * 8;
#pragma unroll
      for (int ks = 0; ks < 4; ++ks) qf[nq][ks] = *(const bf16x8*)(qp + ks * 32);
    }

    f32x4 oacc[2][8] = {};
    float rs[2] = {0.f, 0.f};
    const int jmax = 2 * qt + 2;
    const int jcap = 2 * qt + (wv >> 1);

    for (int j = 0; j < jmax; ++j) {
      const int kv0 = j * 64;
      __syncthreads();
#pragma unroll
      for (int i = 0; i < 4; ++i) {
        int l = i * 256 + tid;
        int r = l >> 4, c = (l & 15) ^ (r & 15);
        async16(&Ks[l * 8], Kg + ((size_t)bh * SEQ + kv0 + r) * HD + c * 8);
      }
#pragma unroll
      for (int i = 0; i < 4; ++i) {
        int l = i * 256 + tid;
        int r = l >> 3, c = (l & 7) ^ (r & 7);
        async16(&Vs[l * 8], Vt + ((size_t)bh * HD + r) * SEQ + kv0 + c * 8);
      }
      __syncthreads();

      if (j <= jcap) {
        const bool edge = (j == jcap);
#pragma unroll
        for (int mi = 0; mi < 4; ++mi) {
          f32x4 st[2] = {};
#pragma unroll
          for (int ks = 0; ks < 4; ++ks) {
            int r = mi * 16 + q15;
            int c = ks * 4 + quad;
            bf16x8 kf = *(const bf16x8*)&Ks[(r * 16 + (c ^ (r & 15))) * 8];
#pragma unroll
            for (int nq = 0; nq < 2; ++nq)
              st[nq] = __builtin_amdgcn_mfma_f32_16x16x32_bf16(kf, qf[nq][ks], st[nq], 0, 0, 0);
          }
#pragma unroll
          for (int nq = 0; nq < 2; ++nq) {
            unsigned int u[4];
#pragma unroll
            for (int r = 0; r < 4; ++r) {
              float p = exp2f(st[nq][r]);
              if (edge) {
                int kv = kv0 + mi * 16 + quad * 4 + r;
                int qq = q0w + nq * 16 + q15;
                p = (kv > qq) ? 0.f : p;
              }
              unsigned int uu = __builtin_bit_cast(unsigned int, p) & 0xffff0000u;
              rs[nq] += __builtin_bit_cast(float, uu);
              u[r] = uu;
            }
            uint2 pk;
            pk.x = (u[0] >> 16) | u[1];
            pk.y = (u[2] >> 16) | u[3];
            *(uint2*)&Pw[(nq * 16 + q15) * 72 + mi * 16 + quad * 4] = pk;
          }
        }
#pragma unroll
        for (int ks = 0; ks < 2; ++ks) {
          bf16x8 pf[2];
#pragma unroll
          for (int mq = 0; mq < 2; ++mq)
            pf[mq] = *(const bf16x8*)&Pw[(mq * 16 + q15) * 72 + ks * 32 + quad * 8];
#pragma unroll
          for (int nf = 0; nf < 8; ++nf) {
            int r = nf * 16 + q15;
            int c = ks * 4 + quad;
            bf16x8 vf = *(const bf16x8*)&Vs[(r * 8 + (c ^ (r & 7))) * 8];
#pragma unroll
            for (int mq = 0; mq < 2; ++mq)
              oacc[mq][nf] = __builtin_amdgcn_mfma_f32_16x16x32_bf16(pf[mq], vf, oacc[mq][nf], 0, 0, 0);
          }
        }
      }
    }

    // segment epilogue: reduce row sums across quads, write O
#pragma unroll
    for (int nq = 0; nq < 2; ++nq) {
      rs[nq] += __shfl_xor(rs[nq], 16);
      rs[nq] += __shfl_xor(rs[nq], 32);
    }
#pragma unroll
    for (int mq = 0; mq < 2; ++mq) {
#pragma unroll
      for (int r = 0; r < 4; ++r) {
        float l = __shfl(rs[mq], quad * 4 + r);
        float inv = 1.0f / l;
        int qq = q0w + mq * 16 + quad * 4 + r;
        size_t base = (((size_t)b * SEQ + qq) * NH + h) * HD;
#pragma unroll
        for (int nf = 0; nf < 8; ++nf)
          O[base + nf * 16 + q15] = f2bf(oacc[mq][nf][r] * inv);
      }
    }
  }
}

// ---------------------------------------------------------------- launch
extern "C" void kernel_launch(void* const* d_in, const int* in_sizes, int n_in,
                              void* d_out, int out_size, void* d_ws, size_t ws_size,
                              hipStream_t stream) {
  (void)in_sizes; (void)n_in; (void)out_size; (void)ws_size;
  const float* x  = (const float*)d_in[0];
  const float* Wq = (const float*)d_in[1];
  const float* Wk = (const float*)d_in[2];
  const float* Wv = (const float*)d_in[3];
  const float* Wo = (const float*)d_in[4];
  const float* bo = (const float*)d_in[5];
  float* out = (float*)d_out;

  const size_t XE = (size_t)BATCH * SEQ * DIM;   // 16.7M elems
  const size_t WE = (size_t)DIM * DIM;           // 4.2M elems

  char* p = (char*)d_ws;
  unsigned short* xb   = (unsigned short*)p; p += XE * 2;
  unsigned short* Wall = (unsigned short*)p; p += 4 * WE * 2;  // [Wq|Wk|Wv|Wo], adjacent to xb
  unsigned short* Qg   = (unsigned short*)p; p += XE * 2;
  unsigned short* Kb   = (unsigned short*)p; p += XE * 2;
  unsigned short* Vtb  = (unsigned short*)p; p += XE * 2;
  unsigned short* attn = (unsigned short*)p; p += XE * 2;

  cast_all_kernel<<<(int)(2 * XE / 4 / 256), 256, 0, stream>>>(x, Wq, Wk, Wv, Wo, xb);

  gemm_qkv<<<dim3(48, 64), 256, 0, stream>>>(
      xb, Wall, Wall + WE, Wall + 2 * WE, Qg, Kb, Vtb);

  attn_kernel<<<dim3(768), 256, 0, stream>>>(Qg, Kb, Vtb, attn);

  gemm_out<<<dim3(DIM / 128, (BATCH * SEQ) / 128), 256, 0, stream>>>(
      attn, Wall + 3 * WE, out, bo);
}